// Round 24
// baseline (120.712 us; speedup 1.0000x reference)
//
#include <hip/hip_runtime.h>
#include <hip/hip_fp16.h>

static constexpr float SLOPE = 0.2f;

#define NPB 128          // nodes per bucket
#define NBMAX 1024       // max buckets
#define CAP 5632         // packed-edge capacity per bucket (avg ~4096, +24 sigma)
#define EPB 8192         // edges per bin block
#define EPT 11           // edges per aggr thread (512 x 11 = 5632 = CAP)

// ---------------------------------------------------------------------------
// Monotone float<->uint key for exact atomicMax on floats of either sign.
__device__ __forceinline__ unsigned fkey(float f) {
    unsigned u = __float_as_uint(f);
    return (u & 0x80000000u) ? ~u : (u | 0x80000000u);
}
__device__ __forceinline__ float fdekey(unsigned k) {
    unsigned u = (k & 0x80000000u) ? (k & 0x7FFFFFFFu) : ~k;
    return __uint_as_float(u);
}

__device__ __forceinline__ int load_idx(const void* ei, int is64, long long pos) {
    return is64 ? (int)((const long long*)ei)[pos] : ((const int*)ei)[pos];
}

// ---------------------------------------------------------------------------
// Zero the bfill workspace (ws is not re-poisoned between replays).
__global__ void zero_kernel(int* __restrict__ bfill) {
    int t = threadIdx.x;
    for (int i = t; i < NBMAX; i += 256) bfill[i] = 0;
}

// ---------------------------------------------------------------------------
// Pass 1: bin edges by dst bucket (bucket = d>>7, 128 nodes). LDS-staged
// sort-by-bucket write-out (histogram -> scan -> LDS place -> bulk reserve
// -> linear write-out). 1024-thread blocks, EPB=8192; ~10.5 words/bucket
// region per block (some write fragmentation accepted for 2x aggr grid).
__global__ void __launch_bounds__(1024) bin_kernel(
        const void* __restrict__ ei, int* __restrict__ bfill,
        unsigned int* __restrict__ packed, int e, int nb) {
    __shared__ int hist[NBMAX];            // counts, then gbase after reserve
    __shared__ int lbase[NBMAX];           // local exclusive scan
    __shared__ int cur[NBMAX];             // placement cursor
    __shared__ unsigned staged[EPB];       // 32KB bucket-sorted packed words
    __shared__ unsigned short sbkt[EPB];   // 16KB bucket id per slot
    __shared__ int sflag;
    int t = threadIdx.x;
    if (t < 64) {
        unsigned hi = ((const unsigned*)ei)[2 * t + 1];
        unsigned long long b = __ballot(hi != 0u);
        if (t == 0) sflag = (b == 0ull) ? 1 : 0;
    }
    if (t < NBMAX) hist[t] = 0;
    __syncthreads();
    int is64 = sflag;
    long long e0 = (long long)blockIdx.x * EPB;
    int cnt = (int)min((long long)EPB, (long long)e - e0);
    // phase A: load 8 contiguous edges/thread into registers + histogram
    int sr[8], dr[8];
    if (!is64 && t * 8 + 7 < cnt) {
        const uint4* ps = (const uint4*)((const int*)ei + e0) + t * 2;
        const uint4* pd = (const uint4*)((const int*)ei + e + e0) + t * 2;
        uint4 s0 = ps[0], s1 = ps[1], d0 = pd[0], d1 = pd[1];
        sr[0] = s0.x; sr[1] = s0.y; sr[2] = s0.z; sr[3] = s0.w;
        sr[4] = s1.x; sr[5] = s1.y; sr[6] = s1.z; sr[7] = s1.w;
        dr[0] = d0.x; dr[1] = d0.y; dr[2] = d0.z; dr[3] = d0.w;
        dr[4] = d1.x; dr[5] = d1.y; dr[6] = d1.z; dr[7] = d1.w;
    } else {
#pragma unroll
        for (int r = 0; r < 8; ++r) {
            int i = t * 8 + r;
            dr[r] = -1;
            if (i < cnt) {
                sr[r] = load_idx(ei, is64, e0 + i);
                dr[r] = load_idx(ei, is64, (long long)e + e0 + i);
            }
        }
    }
#pragma unroll
    for (int r = 0; r < 8; ++r)
        if (dr[r] >= 0) atomicAdd(&hist[dr[r] >> 7], 1);
    __syncthreads();
    // block-local exclusive scan over NBMAX buckets (thread t owns bucket t)
    int v = (t < NBMAX) ? hist[t] : 0;
    if (t < NBMAX) lbase[t] = v;
    __syncthreads();
    for (int off = 1; off < NBMAX; off <<= 1) {
        int y = (t < NBMAX && t >= off) ? lbase[t - off] : 0;
        __syncthreads();
        if (t < NBMAX) lbase[t] += y;
        __syncthreads();
    }
    if (t < NBMAX) {
        lbase[t] -= v;          // exclusive
        cur[t] = lbase[t];
        hist[t] = (v > 0) ? atomicAdd(&bfill[t], v) : 0;  // hist becomes gbase
    }
    __syncthreads();
    // phase B: place into LDS staged, sorted by bucket
#pragma unroll
    for (int r = 0; r < 8; ++r) {
        if (dr[r] >= 0) {
            int bk = dr[r] >> 7;
            int lp = atomicAdd(&cur[bk], 1);
            staged[lp] = ((unsigned)(dr[r] & 127) << 17) | (unsigned)sr[r];
            sbkt[lp] = (unsigned short)bk;
        }
    }
    __syncthreads();
    // phase C: coalesced linear write-out
    for (int i = t; i < cnt; i += 1024) {
        int bk = sbkt[i];
        int within = hist[bk] + (i - lbase[bk]);
        if (within < CAP)
            packed[(long long)bk * CAP + within] = staged[i];
    }
}

// ---------------------------------------------------------------------------
// Per-node feature transform (layer 1 only): h = x @ W; alpha dots.
// Writes h in fp32 (self-term) AND fp16 (h16, 3.2MB gather table).
template <int NF>
__global__ void feat_kernel(const float* __restrict__ x, const float* __restrict__ W,
                            const float* __restrict__ avs, const float* __restrict__ avd,
                            float* __restrict__ h, __half* __restrict__ h16,
                            float* __restrict__ as, float* __restrict__ ad, int n) {
    __shared__ float sW[NF * 16];
    __shared__ float sa[32];
    int t = threadIdx.x;
    if (t < NF * 16) sW[t] = W[t];
    if (t < 16) sa[t] = avs[t];
    else if (t < 32) sa[t] = avd[t - 16];
    __syncthreads();
    int nid = blockIdx.x * blockDim.x + t;
    if (nid >= n) return;
    float xi[NF];
#pragma unroll
    for (int f = 0; f < NF; ++f) xi[f] = x[(long long)nid * NF + f];
    float hv[16];
    float s1 = 0.f, s2 = 0.f;
#pragma unroll
    for (int k = 0; k < 16; ++k) {
        float acc = 0.f;
#pragma unroll
        for (int f = 0; f < NF; ++f) acc = fmaf(xi[f], sW[f * 16 + k], acc);
        hv[k] = acc;
        s1 = fmaf(acc, sa[k], s1);
        s2 = fmaf(acc, sa[16 + k], s2);
    }
    float4* hp = (float4*)(h + (long long)nid * 16);
    hp[0] = make_float4(hv[0], hv[1], hv[2], hv[3]);
    hp[1] = make_float4(hv[4], hv[5], hv[6], hv[7]);
    hp[2] = make_float4(hv[8], hv[9], hv[10], hv[11]);
    hp[3] = make_float4(hv[12], hv[13], hv[14], hv[15]);
    unsigned u[8];
#pragma unroll
    for (int q = 0; q < 8; ++q) {
        __half2 p2 = __halves2half2(__float2half(hv[2 * q]), __float2half(hv[2 * q + 1]));
        u[q] = *(unsigned*)&p2;
    }
    uint4* hp16 = (uint4*)(h16 + (long long)nid * 16);
    hp16[0] = make_uint4(u[0], u[1], u[2], u[3]);
    hp16[1] = make_uint4(u[4], u[5], u[6], u[7]);
    as[nid] = s1;
    ad[nid] = s2;
}

// ---------------------------------------------------------------------------
// EDGE-PARALLEL two-pass softmax aggregation, one 512-thread block per
// 128-node bucket (grid 782 = ~3 blocks/CU: single balanced dispatch round,
// 4 resident blocks/CU overlap each other's barrier/atomic phases — fixes
// the 29% achieved occupancy of the 391x1024 shape). Pass 1: per-node TRUE
// max via one LDS u32 atomicMax per edge (exact, commutative); weights
// w = exp(e - m + 21 ln2) <= 2^21 so per-node channel sums < 2^30 and TWO
// channels fit one u64 atomic: enc = (t1<<32) + (t0 + 2^31), added mod 2^64;
// the addend count (den high word) recovers exact carries at output. 9 u64
// + 1 u32 atomics per edge, iterations fully independent. BITWISE ORDER-
// INDEPENDENT: integer max/add commute exactly. den >= 2^21 => quantization
// ~1.5e-5. FUSE=1: epilogue computes layer-2 feature transform per node
// (o = relu(acc/den + b1); h2 = o @ W2; alpha dots) straight from LDS.
template <int FUSE>
__global__ void __launch_bounds__(512) aggr_kernel(
        const float* __restrict__ h, const __half* __restrict__ h16,
        const float* __restrict__ as, const float* __restrict__ ad,
        const unsigned* __restrict__ packed, const int* __restrict__ bfill,
        const float* __restrict__ bias,
        const float* __restrict__ W2, const float* __restrict__ avs2,
        const float* __restrict__ avd2,
        float* __restrict__ hO, __half* __restrict__ h16O,
        float* __restrict__ asO, float* __restrict__ adO,
        float* __restrict__ out, int n) {
    __shared__ unsigned long long accS[NPB * 9];  // 9KB: +0..7 ch-pairs, +8 cnt|den
    __shared__ unsigned maxS[NPB];                // fkey(per-node max e)
    __shared__ float ccS[NPB];
    __shared__ float adnS[NPB];
    __shared__ float sW2[256];
    __shared__ float sa2[32];
    int b = blockIdx.x, t = threadIdx.x;
    if constexpr (FUSE) {
        if (t < 256) sW2[t] = W2[t];
        else if (t < 272) sa2[t - 256] = avs2[t - 256];
        else if (t < 288) sa2[t - 272 + 16] = avd2[t - 272];
    }
    int cnt = min(bfill[b], CAP);
    long long pb = (long long)b * CAP;
    // (a) init per-node state: adn + max seeded with self score
    if (t < NPB) {
        int node = b * NPB + t;
        float adn = (node < n) ? ad[node] : 0.f;
        adnS[t] = adn;
        float es = (node < n) ? (as[node] + adn) : 0.f;
        es = fmaxf(es, SLOPE * es);
        maxS[t] = fkey(es);
    }
    __syncthreads();
    // (b) pass 1: per-node true max over edges; keep (packed,e) in regs
    unsigned pk[EPT];
    float ev[EPT];
#pragma unroll
    for (int r = 0; r < EPT; ++r) {
        int j = t + (r << 9);
        pk[r] = 0xFFFFFFFFu;
        if (j < cnt) {
            unsigned p = packed[pb + j];
            int dl = p >> 17;
            int s = (int)(p & 0x1FFFF);
            float e2 = as[s] + adnS[dl];
            e2 = fmaxf(e2, SLOPE * e2);
            pk[r] = p;
            ev[r] = e2;
            atomicMax(&maxS[dl], fkey(e2));
        }
    }
    __syncthreads();
    // (c) per-node cc + self term (count starts at 1)
    if (t < NPB) {
        int node = b * NPB + t;
        if (node < n) {
            float m = fdekey(maxS[t]);
            float cc = 21.f * 0.69314718f - m;   // w = exp(e+cc) <= 2^21
            ccS[t] = cc;
            float es = as[node] + adnS[t];
            es = fmaxf(es, SLOPE * es);
            float ws = __expf(es + cc);
            unsigned wsi = (unsigned)(int)ws;
            int base = t * 9;
            const float4* hp = (const float4*)(h + (long long)node * 16);
            float4 h0 = hp[0], h1v = hp[1], h2v = hp[2], h3v = hp[3];
            float hv[16] = {h0.x, h0.y, h0.z, h0.w, h1v.x, h1v.y, h1v.z, h1v.w,
                            h2v.x, h2v.y, h2v.z, h2v.w, h3v.x, h3v.y, h3v.z, h3v.w};
#pragma unroll
            for (int q = 0; q < 8; ++q) {
                int t0 = (int)(ws * hv[2 * q]);
                int t1 = (int)(ws * hv[2 * q + 1]);
                accS[base + q] = ((unsigned long long)(unsigned)t1 << 32) +
                                 (unsigned long long)((unsigned)t0 + 0x80000000u);
            }
            accS[base + 8] = (1ull << 32) | wsi;  // count=1, den=ws
        }
    }
    __syncthreads();
    // (d) pass 2: exp + packed-pair atomics (9 u64, independent iterations)
#pragma unroll
    for (int r = 0; r < EPT; ++r) {
        if (pk[r] != 0xFFFFFFFFu) {
            unsigned p = pk[r];
            int dl = p >> 17;
            int s = (int)(p & 0x1FFFF);
            float w = __expf(ev[r] + ccS[dl]);
            unsigned wi = (unsigned)(int)w;
            int base = dl * 9;
            atomicAdd(&accS[base + 8], (1ull << 32) | wi);
            const uint4* hr = (const uint4*)(h16 + (long long)s * 16);
            uint4 r0 = hr[0], r1 = hr[1];
            unsigned rr[8] = {r0.x, r0.y, r0.z, r0.w, r1.x, r1.y, r1.z, r1.w};
#pragma unroll
            for (int q = 0; q < 8; ++q) {
                float2 f = __half22float2(*(__half2*)&rr[q]);
                int t0 = (int)(w * f.x);
                int t1 = (int)(w * f.y);
                unsigned long long enc =
                    ((unsigned long long)(unsigned)t1 << 32) +
                    (unsigned long long)((unsigned)t0 + 0x80000000u);
                atomicAdd(&accS[base + q], enc);
            }
        }
    }
    __syncthreads();
    // (e) output
    if constexpr (FUSE) {
        // layer-1 finish + fused layer-2 feature transform, per node
        if (t < NPB) {
            int node = b * NPB + t;
            if (node < n) {
                unsigned long long dpack = accS[t * 9 + 8];
                unsigned kcnt = (unsigned)(dpack >> 32);
                float den = (float)(unsigned)dpack;
                float o[16];
#pragma unroll
                for (int q = 0; q < 8; ++q) {
                    unsigned long long a = accS[t * 9 + q];
                    unsigned lo = (unsigned)a, hi = (unsigned)(a >> 32);
                    int s0 = (int)(lo - (kcnt << 31));
                    long long carries =
                        ((((long long)kcnt) << 31) + (long long)s0) >> 32;
                    int s1v = (int)(hi - (unsigned)carries);
                    o[2 * q]     = fmaxf((float)s0  / den + bias[2 * q], 0.f);
                    o[2 * q + 1] = fmaxf((float)s1v / den + bias[2 * q + 1], 0.f);
                }
                float hv[16];
                float d1 = 0.f, d2 = 0.f;
#pragma unroll
                for (int k = 0; k < 16; ++k) {
                    float acc = 0.f;
#pragma unroll
                    for (int f = 0; f < 16; ++f)
                        acc = fmaf(o[f], sW2[f * 16 + k], acc);
                    hv[k] = acc;
                    d1 = fmaf(acc, sa2[k], d1);
                    d2 = fmaf(acc, sa2[16 + k], d2);
                }
                float4* hp = (float4*)(hO + (long long)node * 16);
                hp[0] = make_float4(hv[0], hv[1], hv[2], hv[3]);
                hp[1] = make_float4(hv[4], hv[5], hv[6], hv[7]);
                hp[2] = make_float4(hv[8], hv[9], hv[10], hv[11]);
                hp[3] = make_float4(hv[12], hv[13], hv[14], hv[15]);
                unsigned u[8];
#pragma unroll
                for (int q = 0; q < 8; ++q) {
                    __half2 p2 = __halves2half2(__float2half(hv[2 * q]),
                                                __float2half(hv[2 * q + 1]));
                    u[q] = *(unsigned*)&p2;
                }
                uint4* hp16 = (uint4*)(h16O + (long long)node * 16);
                hp16[0] = make_uint4(u[0], u[1], u[2], u[3]);
                hp16[1] = make_uint4(u[4], u[5], u[6], u[7]);
                asO[node] = d1;
                adO[node] = d2;
            }
        }
    } else {
        // final layer: unpack, divide, bias (no relu), coalesced store
        for (int idx = t; idx < NPB * 16; idx += 512) {
            int i = idx >> 4, k = idx & 15;
            int node = b * NPB + i;
            if (node < n) {
                unsigned long long dpack = accS[i * 9 + 8];
                unsigned kcnt = (unsigned)(dpack >> 32);
                float den = (float)(unsigned)dpack;
                unsigned long long a = accS[i * 9 + (k >> 1)];
                unsigned lo = (unsigned)a, hi = (unsigned)(a >> 32);
                int s0 = (int)(lo - (kcnt << 31));
                float val;
                if ((k & 1) == 0) {
                    val = (float)s0;
                } else {
                    long long carries =
                        ((((long long)kcnt) << 31) + (long long)s0) >> 32;
                    int s1v = (int)(hi - (unsigned)carries);
                    val = (float)s1v;
                }
                out[(long long)node * 16 + k] = val / den + bias[k];
            }
        }
    }
}

// ---------------------------------------------------------------------------
extern "C" void kernel_launch(void* const* d_in, const int* in_sizes, int n_in,
                              void* d_out, int out_size, void* d_ws, size_t ws_size,
                              hipStream_t stream) {
    const float* x  = (const float*)d_in[0];
    const void*  ei = d_in[1];
    const float* W1  = (const float*)d_in[2];
    const float* as1 = (const float*)d_in[3];
    const float* ad1 = (const float*)d_in[4];
    const float* b1  = (const float*)d_in[5];
    const float* W2  = (const float*)d_in[6];
    const float* as2 = (const float*)d_in[7];
    const float* ad2 = (const float*)d_in[8];
    const float* b2  = (const float*)d_in[9];
    float* out = (float*)d_out;

    const int n = in_sizes[0] / 14;      // 100000
    const int e = in_sizes[1] / 2;       // 3200000
    const int nb = (n + NPB - 1) / NPB;  // 782 buckets

    char* p = (char*)d_ws;
    auto alloc = [&](size_t bytes) {
        char* r = p;
        p += (bytes + 255) & ~(size_t)255;
        return r;
    };
    int*      bfill  = (int*)alloc(NBMAX * 4);
    unsigned* packed = (unsigned*)alloc((size_t)nb * CAP * 4);
    float*    hA     = (float*)alloc((size_t)n * 16 * 4);
    __half*   h16A   = (__half*)alloc((size_t)n * 16 * 2);
    float*    asA    = (float*)alloc((size_t)n * 4);
    float*    adA    = (float*)alloc((size_t)n * 4);
    float*    hB     = (float*)alloc((size_t)n * 16 * 4);
    __half*   h16B   = (__half*)alloc((size_t)n * 16 * 2);
    float*    asB    = (float*)alloc((size_t)n * 4);
    float*    adB    = (float*)alloc((size_t)n * 4);

    zero_kernel<<<1, 256, 0, stream>>>(bfill);
    bin_kernel<<<(e + EPB - 1) / EPB, 1024, 0, stream>>>(ei, bfill, packed, e, nb);

    // Layer 1 feature transform
    feat_kernel<14><<<(n + 255) / 256, 256, 0, stream>>>(x, W1, as1, ad1, hA, h16A, asA, adA, n);
    // Layer-1 aggregation fused with layer-2 feature transform
    aggr_kernel<1><<<nb, 512, 0, stream>>>(hA, h16A, asA, adA, packed, bfill, b1,
                                           W2, as2, ad2, hB, h16B, asB, adB,
                                           nullptr, n);
    // Layer-2 aggregation -> final output
    aggr_kernel<0><<<nb, 512, 0, stream>>>(hB, h16B, asB, adB, packed, bfill, b2,
                                           nullptr, nullptr, nullptr,
                                           nullptr, nullptr, nullptr, nullptr,
                                           out, n);
}

// Round 25
// 120.571 us; speedup vs baseline: 1.0012x; 1.0012x over previous
//
#include <hip/hip_runtime.h>
#include <hip/hip_fp16.h>

static constexpr float SLOPE = 0.2f;

#define NPB 256          // nodes per bucket
#define NBMAX 512        // max buckets
#define CAP 10240        // packed-edge capacity per bucket (avg ~8184, >20 sigma margin)
#define EPB 8192         // edges per bin block (~21 words/bucket region, line-coalesced)
#define EPT 10           // edges per aggr thread (1024 x 10 = CAP)

// ---------------------------------------------------------------------------
// Monotone float<->uint key for exact atomicMax on floats of either sign.
__device__ __forceinline__ unsigned fkey(float f) {
    unsigned u = __float_as_uint(f);
    return (u & 0x80000000u) ? ~u : (u | 0x80000000u);
}
__device__ __forceinline__ float fdekey(unsigned k) {
    unsigned u = (k & 0x80000000u) ? (k & 0x7FFFFFFFu) : ~k;
    return __uint_as_float(u);
}

__device__ __forceinline__ int load_idx(const void* ei, int is64, long long pos) {
    return is64 ? (int)((const long long*)ei)[pos] : ((const int*)ei)[pos];
}

// ---------------------------------------------------------------------------
// Zero the bfill workspace (ws is not re-poisoned between replays).
__global__ void zero_kernel(int* __restrict__ bfill) {
    int t = threadIdx.x;
    for (int i = t; i < NBMAX; i += 256) bfill[i] = 0;
}

// ---------------------------------------------------------------------------
// Pass 1: bin edges by dst bucket. LDS-staged sort-by-bucket write-out
// (histogram -> scan -> LDS place -> bulk reserve -> linear write-out).
// 1024-thread blocks, EPB=8192 (validated R21/R23 config).
__global__ void __launch_bounds__(1024) bin_kernel(
        const void* __restrict__ ei, int* __restrict__ bfill,
        unsigned int* __restrict__ packed, int e, int nb) {
    __shared__ int hist[NBMAX];            // counts, then gbase after reserve
    __shared__ int lbase[NBMAX];           // local exclusive scan
    __shared__ int cur[NBMAX];             // placement cursor
    __shared__ unsigned staged[EPB];       // 32KB bucket-sorted packed words
    __shared__ unsigned short sbkt[EPB];   // 16KB bucket id per slot
    __shared__ int sflag;
    int t = threadIdx.x;
    if (t < 64) {
        unsigned hi = ((const unsigned*)ei)[2 * t + 1];
        unsigned long long b = __ballot(hi != 0u);
        if (t == 0) sflag = (b == 0ull) ? 1 : 0;
    }
    if (t < NBMAX) hist[t] = 0;
    __syncthreads();
    int is64 = sflag;
    long long e0 = (long long)blockIdx.x * EPB;
    int cnt = (int)min((long long)EPB, (long long)e - e0);
    // phase A: load 8 contiguous edges/thread into registers + histogram
    int sr[8], dr[8];
    if (!is64 && t * 8 + 7 < cnt) {
        const uint4* ps = (const uint4*)((const int*)ei + e0) + t * 2;
        const uint4* pd = (const uint4*)((const int*)ei + e + e0) + t * 2;
        uint4 s0 = ps[0], s1 = ps[1], d0 = pd[0], d1 = pd[1];
        sr[0] = s0.x; sr[1] = s0.y; sr[2] = s0.z; sr[3] = s0.w;
        sr[4] = s1.x; sr[5] = s1.y; sr[6] = s1.z; sr[7] = s1.w;
        dr[0] = d0.x; dr[1] = d0.y; dr[2] = d0.z; dr[3] = d0.w;
        dr[4] = d1.x; dr[5] = d1.y; dr[6] = d1.z; dr[7] = d1.w;
    } else {
#pragma unroll
        for (int r = 0; r < 8; ++r) {
            int i = t * 8 + r;
            dr[r] = -1;
            if (i < cnt) {
                sr[r] = load_idx(ei, is64, e0 + i);
                dr[r] = load_idx(ei, is64, (long long)e + e0 + i);
            }
        }
    }
#pragma unroll
    for (int r = 0; r < 8; ++r)
        if (dr[r] >= 0) atomicAdd(&hist[dr[r] >> 8], 1);
    __syncthreads();
    // block-local exclusive scan over NBMAX buckets (thread t owns bucket t)
    int v = (t < NBMAX) ? hist[t] : 0;
    if (t < NBMAX) lbase[t] = v;
    __syncthreads();
    for (int off = 1; off < NBMAX; off <<= 1) {
        int y = (t < NBMAX && t >= off) ? lbase[t - off] : 0;
        __syncthreads();
        if (t < NBMAX) lbase[t] += y;
        __syncthreads();
    }
    if (t < NBMAX) {
        lbase[t] -= v;          // exclusive
        cur[t] = lbase[t];
        hist[t] = (v > 0) ? atomicAdd(&bfill[t], v) : 0;  // hist becomes gbase
    }
    __syncthreads();
    // phase B: place into LDS staged, sorted by bucket
#pragma unroll
    for (int r = 0; r < 8; ++r) {
        if (dr[r] >= 0) {
            int bk = dr[r] >> 8;
            int lp = atomicAdd(&cur[bk], 1);
            staged[lp] = ((unsigned)(dr[r] & 255) << 17) | (unsigned)sr[r];
            sbkt[lp] = (unsigned short)bk;
        }
    }
    __syncthreads();
    // phase C: coalesced linear write-out
    for (int i = t; i < cnt; i += 1024) {
        int bk = sbkt[i];
        int within = hist[bk] + (i - lbase[bk]);
        if (within < CAP)
            packed[(long long)bk * CAP + within] = staged[i];
    }
}

// ---------------------------------------------------------------------------
// Per-node feature transform (layer 1 only): h = x @ W; alpha dots.
// Writes h in fp32 (self-term) AND fp16 (h16, 3.2MB gather table).
template <int NF>
__global__ void feat_kernel(const float* __restrict__ x, const float* __restrict__ W,
                            const float* __restrict__ avs, const float* __restrict__ avd,
                            float* __restrict__ h, __half* __restrict__ h16,
                            float* __restrict__ as, float* __restrict__ ad, int n) {
    __shared__ float sW[NF * 16];
    __shared__ float sa[32];
    int t = threadIdx.x;
    if (t < NF * 16) sW[t] = W[t];
    if (t < 16) sa[t] = avs[t];
    else if (t < 32) sa[t] = avd[t - 16];
    __syncthreads();
    int nid = blockIdx.x * blockDim.x + t;
    if (nid >= n) return;
    float xi[NF];
#pragma unroll
    for (int f = 0; f < NF; ++f) xi[f] = x[(long long)nid * NF + f];
    float hv[16];
    float s1 = 0.f, s2 = 0.f;
#pragma unroll
    for (int k = 0; k < 16; ++k) {
        float acc = 0.f;
#pragma unroll
        for (int f = 0; f < NF; ++f) acc = fmaf(xi[f], sW[f * 16 + k], acc);
        hv[k] = acc;
        s1 = fmaf(acc, sa[k], s1);
        s2 = fmaf(acc, sa[16 + k], s2);
    }
    float4* hp = (float4*)(h + (long long)nid * 16);
    hp[0] = make_float4(hv[0], hv[1], hv[2], hv[3]);
    hp[1] = make_float4(hv[4], hv[5], hv[6], hv[7]);
    hp[2] = make_float4(hv[8], hv[9], hv[10], hv[11]);
    hp[3] = make_float4(hv[12], hv[13], hv[14], hv[15]);
    unsigned u[8];
#pragma unroll
    for (int q = 0; q < 8; ++q) {
        __half2 p2 = __halves2half2(__float2half(hv[2 * q]), __float2half(hv[2 * q + 1]));
        u[q] = *(unsigned*)&p2;
    }
    uint4* hp16 = (uint4*)(h16 + (long long)nid * 16);
    hp16[0] = make_uint4(u[0], u[1], u[2], u[3]);
    hp16[1] = make_uint4(u[4], u[5], u[6], u[7]);
    as[nid] = s1;
    ad[nid] = s2;
}

// ---------------------------------------------------------------------------
// EDGE-PARALLEL two-pass softmax aggregation, one 1024-thread block per
// 256-node bucket, SOFTWARE-PIPELINED: pass 1 is staged (all 10 packed loads
// issued, then all 10 as gathers, then leaky+atomicMax) so 10 VMEM are in
// flight instead of 1; pass 2 computes all 10 exps upfront, then runs a
// 2-deep static-register pipeline on the h16 row loads — iteration r's
// prefetch of row r+1 issues BEFORE r's 9-atomic LDS burst, hiding the L2
// gather latency under the atomic traffic (the in-order wave otherwise
// serializes load->atomics per edge; VGPR 36 showed the compiler hoisted
// nothing). Numerics identical to R21/R23: per-node TRUE max via u32
// atomicMax (exact); w = exp(e - m + 21 ln2) <= 2^21 so channel-pair sums
// < 2^30 and TWO channels ride one u64 atomic (enc = (t1<<32)+(t0+2^31));
// count in den's high word recovers exact carries. BITWISE ORDER-
// INDEPENDENT: integer max/add commute exactly. den >= 2^21 => ~1.5e-5.
// FUSE=1: epilogue computes layer-2 feature transform per node from LDS.
template <int FUSE>
__global__ void __launch_bounds__(1024) aggr_kernel(
        const float* __restrict__ h, const __half* __restrict__ h16,
        const float* __restrict__ as, const float* __restrict__ ad,
        const unsigned* __restrict__ packed, const int* __restrict__ bfill,
        const float* __restrict__ bias,
        const float* __restrict__ W2, const float* __restrict__ avs2,
        const float* __restrict__ avd2,
        float* __restrict__ hO, __half* __restrict__ h16O,
        float* __restrict__ asO, float* __restrict__ adO,
        float* __restrict__ out, int n) {
    __shared__ unsigned long long accS[NPB * 9];  // 18KB: +0..7 ch-pairs, +8 cnt|den
    __shared__ unsigned maxS[NPB];                // fkey(per-node max e)
    __shared__ float ccS[NPB];
    __shared__ float adnS[NPB];
    __shared__ float sW2[256];
    __shared__ float sa2[32];
    int b = blockIdx.x, t = threadIdx.x;
    if constexpr (FUSE) {
        if (t < 256) sW2[t] = W2[t];
        else if (t < 272) sa2[t - 256] = avs2[t - 256];
        else if (t < 288) sa2[t - 272 + 16] = avd2[t - 272];
    }
    int cnt = min(bfill[b], CAP);
    long long pb = (long long)b * CAP;
    // (a) init per-node state: adn + max seeded with self score
    if (t < NPB) {
        int node = b * NPB + t;
        float adn = (node < n) ? ad[node] : 0.f;
        adnS[t] = adn;
        float es = (node < n) ? (as[node] + adn) : 0.f;
        es = fmaxf(es, SLOPE * es);
        maxS[t] = fkey(es);
    }
    __syncthreads();
    // (b) pass 1, staged: [all packed loads] -> [all as gathers] -> max
    unsigned pk[EPT];
    float asv[EPT];
    float ev[EPT];
#pragma unroll
    for (int r = 0; r < EPT; ++r) {
        int j = t + (r << 10);
        pk[r] = 0xFFFFFFFFu;
        if (j < cnt) pk[r] = packed[pb + j];
    }
#pragma unroll
    for (int r = 0; r < EPT; ++r)
        if (pk[r] != 0xFFFFFFFFu) asv[r] = as[pk[r] & 0x1FFFF];
#pragma unroll
    for (int r = 0; r < EPT; ++r) {
        if (pk[r] != 0xFFFFFFFFu) {
            int dl = pk[r] >> 17;
            float e2 = asv[r] + adnS[dl];
            e2 = fmaxf(e2, SLOPE * e2);
            ev[r] = e2;
            atomicMax(&maxS[dl], fkey(e2));
        }
    }
    __syncthreads();
    // (c) per-node cc + self term (count starts at 1)
    if (t < NPB) {
        int node = b * NPB + t;
        if (node < n) {
            float m = fdekey(maxS[t]);
            float cc = 21.f * 0.69314718f - m;   // w = exp(e+cc) <= 2^21
            ccS[t] = cc;
            float es = as[node] + adnS[t];
            es = fmaxf(es, SLOPE * es);
            float ws = __expf(es + cc);
            unsigned wsi = (unsigned)(int)ws;
            int base = t * 9;
            const float4* hp = (const float4*)(h + (long long)node * 16);
            float4 h0 = hp[0], h1v = hp[1], h2v = hp[2], h3v = hp[3];
            float hv[16] = {h0.x, h0.y, h0.z, h0.w, h1v.x, h1v.y, h1v.z, h1v.w,
                            h2v.x, h2v.y, h2v.z, h2v.w, h3v.x, h3v.y, h3v.z, h3v.w};
#pragma unroll
            for (int q = 0; q < 8; ++q) {
                int t0 = (int)(ws * hv[2 * q]);
                int t1 = (int)(ws * hv[2 * q + 1]);
                accS[base + q] = ((unsigned long long)(unsigned)t1 << 32) +
                                 (unsigned long long)((unsigned)t0 + 0x80000000u);
            }
            accS[base + 8] = (1ull << 32) | wsi;  // count=1, den=ws
        }
    }
    __syncthreads();
    // (d) pass 2: exps upfront; 2-deep row pipeline; 9 u64 atomics per edge
    float wv[EPT];
#pragma unroll
    for (int r = 0; r < EPT; ++r)
        wv[r] = (pk[r] != 0xFFFFFFFFu)
                    ? __expf(ev[r] + ccS[pk[r] >> 17]) : 0.f;
    uint4 nxt0 = {}, nxt1 = {};
    if (pk[0] != 0xFFFFFFFFu) {
        const uint4* hr = (const uint4*)(h16 + (long long)(pk[0] & 0x1FFFF) * 16);
        nxt0 = hr[0];
        nxt1 = hr[1];
    }
#pragma unroll
    for (int r = 0; r < EPT; ++r) {
        uint4 cur0 = nxt0, cur1 = nxt1;
        if (r + 1 < EPT && pk[r + 1] != 0xFFFFFFFFu) {
            const uint4* hr =
                (const uint4*)(h16 + (long long)(pk[r + 1] & 0x1FFFF) * 16);
            nxt0 = hr[0];
            nxt1 = hr[1];
        }
        if (pk[r] != 0xFFFFFFFFu) {
            float w = wv[r];
            int base = (int)(pk[r] >> 17) * 9;
            atomicAdd(&accS[base + 8], (1ull << 32) | (unsigned)(int)w);
            unsigned rr[8] = {cur0.x, cur0.y, cur0.z, cur0.w,
                              cur1.x, cur1.y, cur1.z, cur1.w};
#pragma unroll
            for (int q = 0; q < 8; ++q) {
                float2 f = __half22float2(*(__half2*)&rr[q]);
                int t0 = (int)(w * f.x);
                int t1 = (int)(w * f.y);
                unsigned long long enc =
                    ((unsigned long long)(unsigned)t1 << 32) +
                    (unsigned long long)((unsigned)t0 + 0x80000000u);
                atomicAdd(&accS[base + q], enc);
            }
        }
    }
    __syncthreads();
    // (e) output
    if constexpr (FUSE) {
        // layer-1 finish + fused layer-2 feature transform, per node
        if (t < NPB) {
            int node = b * NPB + t;
            if (node < n) {
                unsigned long long dpack = accS[t * 9 + 8];
                unsigned kcnt = (unsigned)(dpack >> 32);
                float den = (float)(unsigned)dpack;
                float o[16];
#pragma unroll
                for (int q = 0; q < 8; ++q) {
                    unsigned long long a = accS[t * 9 + q];
                    unsigned lo = (unsigned)a, hi = (unsigned)(a >> 32);
                    int s0 = (int)(lo - (kcnt << 31));
                    long long carries =
                        ((((long long)kcnt) << 31) + (long long)s0) >> 32;
                    int s1v = (int)(hi - (unsigned)carries);
                    o[2 * q]     = fmaxf((float)s0  / den + bias[2 * q], 0.f);
                    o[2 * q + 1] = fmaxf((float)s1v / den + bias[2 * q + 1], 0.f);
                }
                float hv[16];
                float d1 = 0.f, d2 = 0.f;
#pragma unroll
                for (int k = 0; k < 16; ++k) {
                    float acc = 0.f;
#pragma unroll
                    for (int f = 0; f < 16; ++f)
                        acc = fmaf(o[f], sW2[f * 16 + k], acc);
                    hv[k] = acc;
                    d1 = fmaf(acc, sa2[k], d1);
                    d2 = fmaf(acc, sa2[16 + k], d2);
                }
                float4* hp = (float4*)(hO + (long long)node * 16);
                hp[0] = make_float4(hv[0], hv[1], hv[2], hv[3]);
                hp[1] = make_float4(hv[4], hv[5], hv[6], hv[7]);
                hp[2] = make_float4(hv[8], hv[9], hv[10], hv[11]);
                hp[3] = make_float4(hv[12], hv[13], hv[14], hv[15]);
                unsigned u[8];
#pragma unroll
                for (int q = 0; q < 8; ++q) {
                    __half2 p2 = __halves2half2(__float2half(hv[2 * q]),
                                                __float2half(hv[2 * q + 1]));
                    u[q] = *(unsigned*)&p2;
                }
                uint4* hp16 = (uint4*)(h16O + (long long)node * 16);
                hp16[0] = make_uint4(u[0], u[1], u[2], u[3]);
                hp16[1] = make_uint4(u[4], u[5], u[6], u[7]);
                asO[node] = d1;
                adO[node] = d2;
            }
        }
    } else {
        // final layer: unpack, divide, bias (no relu), coalesced store
        for (int idx = t; idx < NPB * 16; idx += 1024) {
            int i = idx >> 4, k = idx & 15;
            int node = b * NPB + i;
            if (node < n) {
                unsigned long long dpack = accS[i * 9 + 8];
                unsigned kcnt = (unsigned)(dpack >> 32);
                float den = (float)(unsigned)dpack;
                unsigned long long a = accS[i * 9 + (k >> 1)];
                unsigned lo = (unsigned)a, hi = (unsigned)(a >> 32);
                int s0 = (int)(lo - (kcnt << 31));
                float val;
                if ((k & 1) == 0) {
                    val = (float)s0;
                } else {
                    long long carries =
                        ((((long long)kcnt) << 31) + (long long)s0) >> 32;
                    int s1v = (int)(hi - (unsigned)carries);
                    val = (float)s1v;
                }
                out[(long long)node * 16 + k] = val / den + bias[k];
            }
        }
    }
}

// ---------------------------------------------------------------------------
extern "C" void kernel_launch(void* const* d_in, const int* in_sizes, int n_in,
                              void* d_out, int out_size, void* d_ws, size_t ws_size,
                              hipStream_t stream) {
    const float* x  = (const float*)d_in[0];
    const void*  ei = d_in[1];
    const float* W1  = (const float*)d_in[2];
    const float* as1 = (const float*)d_in[3];
    const float* ad1 = (const float*)d_in[4];
    const float* b1  = (const float*)d_in[5];
    const float* W2  = (const float*)d_in[6];
    const float* as2 = (const float*)d_in[7];
    const float* ad2 = (const float*)d_in[8];
    const float* b2  = (const float*)d_in[9];
    float* out = (float*)d_out;

    const int n = in_sizes[0] / 14;      // 100000
    const int e = in_sizes[1] / 2;       // 3200000
    const int nb = (n + NPB - 1) / NPB;  // 391 buckets

    char* p = (char*)d_ws;
    auto alloc = [&](size_t bytes) {
        char* r = p;
        p += (bytes + 255) & ~(size_t)255;
        return r;
    };
    int*      bfill  = (int*)alloc(NBMAX * 4);
    unsigned* packed = (unsigned*)alloc((size_t)nb * CAP * 4);
    float*    hA     = (float*)alloc((size_t)n * 16 * 4);
    __half*   h16A   = (__half*)alloc((size_t)n * 16 * 2);
    float*    asA    = (float*)alloc((size_t)n * 4);
    float*    adA    = (float*)alloc((size_t)n * 4);
    float*    hB     = (float*)alloc((size_t)n * 16 * 4);
    __half*   h16B   = (__half*)alloc((size_t)n * 16 * 2);
    float*    asB    = (float*)alloc((size_t)n * 4);
    float*    adB    = (float*)alloc((size_t)n * 4);

    zero_kernel<<<1, 256, 0, stream>>>(bfill);
    bin_kernel<<<(e + EPB - 1) / EPB, 1024, 0, stream>>>(ei, bfill, packed, e, nb);

    // Layer 1 feature transform
    feat_kernel<14><<<(n + 255) / 256, 256, 0, stream>>>(x, W1, as1, ad1, hA, h16A, asA, adA, n);
    // Layer-1 aggregation fused with layer-2 feature transform
    aggr_kernel<1><<<nb, 1024, 0, stream>>>(hA, h16A, asA, adA, packed, bfill, b1,
                                            W2, as2, ad2, hB, h16B, asB, adB,
                                            nullptr, n);
    // Layer-2 aggregation -> final output
    aggr_kernel<0><<<nb, 1024, 0, stream>>>(hB, h16B, asB, adB, packed, bfill, b2,
                                            nullptr, nullptr, nullptr,
                                            nullptr, nullptr, nullptr, nullptr,
                                            out, n);
}